// Round 1
// baseline (24234.998 us; speedup 1.0000x reference)
//
#include <hip/hip_runtime.h>
#include <stdint.h>
#include <math.h>

// Replicates jax.random semantics. PARTITIONABLE=1 -> modern JAX default
// (jax_threefry_partitionable=True, flipped on in jax 0.4.36). If absmax is
// garbage-scale, flip to 0 (legacy iota-split threefry).
#define PARTITIONABLE 1

constexpr int NN = 2048;   // nodes
constexpr int NA = 2048;   // ants
constexpr int NS = 2047;   // steps (N-1)
constexpr uint32_t HALF = 2097152u;  // NN*NA/2, for legacy counter split

struct OvfRec { uint32_t cnt; uint32_t n[16]; float g[16]; };

constexpr int    OVF_CAP   = 16384;
constexpr size_t OFF_KEYS  = 1024;                                  // 4094 u32
constexpr size_t OFF_SLOTS = 32768;                                 // NS*NA u32
constexpr size_t OFF_OVF   = OFF_SLOTS + (size_t)NS * NA * 4;       // 16,801,792
constexpr size_t OFF_PATHS = OFF_OVF + (size_t)OVF_CAP * sizeof(OvfRec);
constexpr size_t OFF_PLEN  = OFF_PATHS + (size_t)NA * NN * 2;
// total ws need ~27.4 MB

// ---- Threefry-2x32, 20 rounds, exactly as in jax/_src/prng.py ----
__device__ __forceinline__ uint2 tf2x32(uint32_t k0, uint32_t k1,
                                        uint32_t x0, uint32_t x1) {
  const uint32_t k2 = k0 ^ k1 ^ 0x1BD11BDAu;
  x0 += k0; x1 += k1;
#define TFR(r) { x0 += x1; x1 = (x1 << (r)) | (x1 >> (32 - (r))); x1 ^= x0; }
  TFR(13) TFR(15) TFR(26) TFR(6)
  x0 += k1; x1 += k2 + 1u;
  TFR(17) TFR(29) TFR(16) TFR(24)
  x0 += k2; x1 += k0 + 2u;
  TFR(13) TFR(15) TFR(26) TFR(6)
  x0 += k0; x1 += k1 + 3u;
  TFR(17) TFR(29) TFR(16) TFR(24)
  x0 += k1; x1 += k2 + 4u;
  TFR(13) TFR(15) TFR(26) TFR(6)
  x0 += k2; x1 += k0 + 5u;
#undef TFR
  return make_uint2(x0, x1);
}

// g = -log(-log(u)) with fp32 intermediate rounding, u from 23-bit mantissa m
// (matches jax uniform(minval=tiny): u==0 -> tiny). Each log computed in
// double then rounded -> correctly-rounded f32, ~XLA's f32 log within 1 ulp.
__device__ __forceinline__ float gumbel_from_m(uint32_t m) {
  float u = __uint_as_float(0x3f800000u | m) - 1.0f;
  if (m == 0u) u = 1.17549435e-38f;
  float t1 = (float)log((double)u);     // < 0
  float t2 = (float)log(-(double)t1);
  return -t2;
}

// ---- per-step key derivation (jax.random.split(key(42), 2047)) ----
__global__ void k_keys(uint32_t* __restrict__ keys) {
  int i = blockIdx.x * 256 + threadIdx.x;
  if (i >= NS) return;
#if PARTITIONABLE
  uint2 o = tf2x32(0u, 42u, 0u, (uint32_t)i);   // key_i = (out0, out1)
  keys[2 * i] = o.x; keys[2 * i + 1] = o.y;
#else
  uint2 o = tf2x32(0u, 42u, (uint32_t)i, (uint32_t)(NS + i));
  keys[i] = o.x; keys[NS + i] = o.y;            // concat(out0,out1) layout
#endif
}

// ---- global max of weights = pher * heur^2 (bounds logit perturbation) ----
__global__ void k_wmax(const float* __restrict__ pher, const float* __restrict__ heur,
                       uint32_t* __restrict__ wmax_bits) {
  int tid = blockIdx.x * blockDim.x + threadIdx.x;
  int stride = gridDim.x * blockDim.x;
  float m = 0.f;
  for (int i = tid; i < NN * NN; i += stride) {
    float h = heur[i];
    m = fmaxf(m, pher[i] * (h * h));
  }
  for (int off = 32; off; off >>= 1) m = fmaxf(m, __shfl_xor(m, off));
  if ((threadIdx.x & 63) == 0) atomicMax((unsigned int*)wmax_bits, __float_as_uint(m));
}

// ---- Phase 1: one wave per (step, ant) row. Computes the 2048 threefry
// values of the row, finds argmax; emits winner, or an overflow record when
// >1 candidate lies within the weight-perturbation window. ----
__global__ __launch_bounds__(256, 4) void k_phase1(
    const uint32_t* __restrict__ keys, const uint32_t* __restrict__ wmax_bits,
    uint32_t* __restrict__ slots, OvfRec* __restrict__ ovf,
    uint32_t* __restrict__ ovf_cnt) {
  struct WBuf { uint32_t cnt; uint32_t cn[32]; uint32_t cm[32]; };
  __shared__ WBuf wb[4];
  const int lane = threadIdx.x & 63;
  const int w    = threadIdx.x >> 6;
  const long wid = (long)blockIdx.x * 4 + w;     // 0 .. NS*NA-1 (grid exact)
  const int s = (int)(wid >> 11);
  const int a = (int)(wid & 2047);
  const uint32_t k0 = keys[2 * s], k1 = keys[2 * s + 1];
  const float wmax = __uint_as_float(*wmax_bits);
  // candidate window in mantissa units: dg/du >= e  =>  du <= (wmax+eps)/e
  const uint32_t W = (uint32_t)((wmax + 1e-5f) * 0.36787944f * 8388608.0f) + 16u;
  if (lane == 0) wb[w].cnt = 0u;

  uint32_t gRaw = 0u;
  const uint32_t base = (uint32_t)a << 11;
#pragma unroll 1
  for (int c = 0; c < 4; ++c) {
    uint32_t craw[8];
    uint32_t cmax = 0u;
#pragma unroll
    for (int i = 0; i < 8; ++i) {
      uint32_t n = (uint32_t)(c << 9) | (uint32_t)(i << 6) | (uint32_t)lane;
      uint32_t bits;
#if PARTITIONABLE
      uint2 o = tf2x32(k0, k1, 0u, base + n);    // ctr = (hi=0, lo=flat)
      bits = o.x ^ o.y;                          // 32-bit fold
#else
      uint32_t j = base + n;
      if (a < 1024) { uint2 o = tf2x32(k0, k1, j, j + HALF); bits = o.x; }
      else          { uint2 o = tf2x32(k0, k1, j - HALF, j); bits = o.y; }
#endif
      craw[i] = bits;
      cmax = max(cmax, bits);
    }
    for (int off = 32; off; off >>= 1) cmax = max(cmax, __shfl_xor(cmax, off));
    gRaw = max(gRaw, cmax);
    uint32_t cm  = cmax >> 9;
    uint32_t cth = cm > W ? cm - W : 0u;   // chunk-max window (superset of final)
#pragma unroll
    for (int i = 0; i < 8; ++i) {
      uint32_t m = craw[i] >> 9;
      if (m >= cth) {
        uint32_t pos = atomicAdd(&wb[w].cnt, 1u);
        if (pos < 32u) {
          wb[w].cn[pos] = (uint32_t)(c << 9) | (uint32_t)(i << 6) | (uint32_t)lane;
          wb[w].cm[pos] = m;
        }
      }
    }
  }
  __syncthreads();

  const uint32_t mstar = gRaw >> 9;
  const uint32_t mth   = mstar > W ? mstar - W : 0u;
  uint32_t cnt = min(wb[w].cnt, 32u);
  bool tight = false; float g = 0.f; uint32_t myn = 0u;
  if ((uint32_t)lane < cnt) {
    uint32_t m = wb[w].cm[lane];
    myn = wb[w].cn[lane];
    if (m >= mth) {
      g = gumbel_from_m(m);
      float gs = gumbel_from_m(mstar);
      tight = (g >= gs - wmax - 1e-5f);   // could this entry win for ANY logits?
    }
  }
  unsigned long long bal = __ballot(tight);
  int tc = __popcll(bal);
  int leader = __ffsll((long long)bal) - 1;
  const size_t slotIdx = (size_t)s * NA + a;
  if (tc == 1) {                 // winner independent of weights/visited
    if (lane == leader) slots[slotIdx] = myn;
  } else if (tc > 1) {           // rare (~1e-4): defer to phase 2
    uint32_t idx = 0u;
    if (lane == leader) idx = atomicAdd(ovf_cnt, 1u);
    idx = (uint32_t)__shfl((int)idx, leader);
    if (idx < (uint32_t)OVF_CAP) {
      if (tight) {
        int pos = __popcll(bal & ((1ull << lane) - 1ull));
        if (pos < 16) { ovf[idx].n[pos] = myn; ovf[idx].g[pos] = g; }
      }
      if (lane == leader) {
        ovf[idx].cnt = (uint32_t)min(tc, 16);
        slots[slotIdx] = 0x80000000u | idx;
      }
    } else if (lane == leader) {
      slots[slotIdx] = myn;      // capacity fallback (never expected)
    }
  } else {                        // tc==0 impossible (max always tight); guard
    if (lane == 0) slots[slotIdx] = mstar & 2047u;
  }
}

// ---- Phase 2: 2048 independent ants replay the sequential walk ----
__global__ __launch_bounds__(256) void k_phase2(
    const uint32_t* __restrict__ slots, const OvfRec* __restrict__ ovf,
    const float* __restrict__ pher, const float* __restrict__ heur,
    const int* __restrict__ antpos, uint16_t* __restrict__ paths,
    float* __restrict__ plen_out) {
  __shared__ uint32_t vis[256][64];    // 64 KB: per-ant visited bitmap
  const int t = threadIdx.x;
  const int a = blockIdx.x * 256 + t;
  for (int i = 0; i < 64; ++i) vis[t][i] = 0u;
  int cur = antpos[a];
  vis[t][cur >> 5] |= 1u << (cur & 31);
  paths[(size_t)a * NN] = (uint16_t)cur;
  float plen = 0.f;
  for (int s = 0; s < NS; ++s) {
    uint32_t slot = slots[(size_t)s * NA + a];
    int nxt;
    if (!(slot & 0x80000000u)) {
      nxt = (int)slot;
    } else {
      const OvfRec& r = ovf[slot & 0x7fffffffu];
      float bs = -INFINITY; int bn = NN;
      int c = (int)r.cnt;
      for (int i = 0; i < c; ++i) {
        int n = (int)r.n[i];
        float wv = 0.f;
        if (((vis[t][n >> 5] >> (n & 31)) & 1u) == 0u) {
          float h = heur[(size_t)cur * NN + n];
          wv = pher[(size_t)cur * NN + n] * (h * h);  // matches p*(h*h) lowering
        }
        float sv = r.g[i] + wv;
        if (sv > bs || (sv == bs && n < bn)) { bs = sv; bn = n; }  // first-idx tie
      }
      nxt = bn;
    }
    plen += heur[(size_t)cur * NN + nxt];   // same fp32 accumulation order as ref
    vis[t][nxt >> 5] |= 1u << (nxt & 31);
    paths[(size_t)a * NN + s + 1] = (uint16_t)nxt;
    cur = nxt;
  }
  plen_out[a] = plen;
}

// ---- Final: argmin plen (first-index tie-break), broadcast best path x8 ----
__global__ void k_final(const float* __restrict__ plen,
                        const uint16_t* __restrict__ paths,
                        float* __restrict__ out) {
  __shared__ unsigned long long wred[4];
  const int t = threadIdx.x;  // 256
  unsigned long long best = ~0ull;
  for (int a = t; a < NA; a += 256) {
    unsigned long long k =
        ((unsigned long long)__float_as_uint(plen[a]) << 32) | (unsigned)a;
    if (k < best) best = k;   // plen >= 0 -> bit order == float order
  }
  for (int off = 32; off; off >>= 1) {
    unsigned long long o = __shfl_xor(best, off);
    if (o < best) best = o;
  }
  if ((t & 63) == 0) wred[t >> 6] = best;
  __syncthreads();
  if (t == 0) {
    unsigned long long b = wred[0];
    for (int i = 1; i < 4; ++i) if (wred[i] < b) b = wred[i];
    wred[0] = b;
  }
  __syncthreads();
  const int bi = (int)(wred[0] & 0xffffffffu);
  const uint16_t* bp = paths + (size_t)bi * NN;
  for (int i = t; i < 8 * NN; i += 256) out[i] = (float)bp[i & (NN - 1)];
}

extern "C" void kernel_launch(void* const* d_in, const int* in_sizes, int n_in,
                              void* d_out, int out_size, void* d_ws, size_t ws_size,
                              hipStream_t stream) {
  (void)in_sizes; (void)n_in; (void)out_size; (void)ws_size;
  const float* pher   = (const float*)d_in[1];
  const float* heur   = (const float*)d_in[2];
  const int*   antpos = (const int*)d_in[3];
  char* ws = (char*)d_ws;
  uint32_t* wmax_bits = (uint32_t*)(ws + 0);
  uint32_t* ovf_cnt   = (uint32_t*)(ws + 4);
  uint32_t* keys      = (uint32_t*)(ws + OFF_KEYS);
  uint32_t* slots     = (uint32_t*)(ws + OFF_SLOTS);
  OvfRec*   ovf       = (OvfRec*)(ws + OFF_OVF);
  uint16_t* paths     = (uint16_t*)(ws + OFF_PATHS);
  float*    plen      = (float*)(ws + OFF_PLEN);

  hipMemsetAsync(d_ws, 0, 64, stream);  // wmax, ovf counter
  hipLaunchKernelGGL(k_keys, dim3(8), dim3(256), 0, stream, keys);
  hipLaunchKernelGGL(k_wmax, dim3(1024), dim3(256), 0, stream, pher, heur, wmax_bits);
  hipLaunchKernelGGL(k_phase1, dim3(NS * NA / 4), dim3(256), 0, stream,
                     keys, wmax_bits, slots, ovf, ovf_cnt);
  hipLaunchKernelGGL(k_phase2, dim3(NA / 256), dim3(256), 0, stream,
                     slots, ovf, pher, heur, antpos, paths, plen);
  hipLaunchKernelGGL(k_final, dim3(1), dim3(256), 0, stream,
                     plen, paths, (float*)d_out);
}

// Round 2
// 16475.435 us; speedup vs baseline: 1.4710x; 1.4710x over previous
//
#include <hip/hip_runtime.h>
#include <stdint.h>
#include <math.h>

constexpr int NN = 2048;   // nodes
constexpr int NA = 2048;   // ants
constexpr int NS = 2047;   // steps (N-1)

struct OvfRec { uint32_t cnt; uint32_t n[16]; float g[16]; };

constexpr int    OVF_CAP   = 32768;
constexpr size_t OFF_KEYS  = 1024;                                  // 4094 u32
constexpr size_t OFF_SLOTS = 32768;                                 // NS*NA u32
constexpr size_t OFF_OVF   = OFF_SLOTS + (size_t)NS * NA * 4;
constexpr size_t OFF_PATHS = OFF_OVF + (size_t)OVF_CAP * sizeof(OvfRec);
constexpr size_t OFF_PLEN  = OFF_PATHS + (size_t)NA * NN * 2;
// total ws ~29.5 MB

// ---- Threefry-2x32, 20 rounds (jax partitionable counter mode) ----
__device__ __forceinline__ uint2 tf2x32(uint32_t k0, uint32_t k1,
                                        uint32_t x0, uint32_t x1) {
  const uint32_t k2 = k0 ^ k1 ^ 0x1BD11BDAu;
  x0 += k0; x1 += k1;
#define TFR(r) { x0 += x1; x1 = __builtin_rotateleft32(x1, r) ^ x0; }
  TFR(13) TFR(15) TFR(26) TFR(6)
  x0 += k1; x1 += k2 + 1u;
  TFR(17) TFR(29) TFR(16) TFR(24)
  x0 += k2; x1 += k0 + 2u;
  TFR(13) TFR(15) TFR(26) TFR(6)
  x0 += k0; x1 += k1 + 3u;
  TFR(17) TFR(29) TFR(16) TFR(24)
  x0 += k1; x1 += k2 + 4u;
  TFR(13) TFR(15) TFR(26) TFR(6)
  x0 += k2; x1 += k0 + 5u;
#undef TFR
  return make_uint2(x0, x1);
}

// g = -log(-log(u)), fp32 intermediate rounding via double log (matches XLA
// f32 log to ~1 ulp); u from 23-bit mantissa m, u==0 -> tiny.
__device__ __forceinline__ float gumbel_from_m(uint32_t m) {
  float u = __uint_as_float(0x3f800000u | m) - 1.0f;
  if (m == 0u) u = 1.17549435e-38f;
  float t1 = (float)log((double)u);
  float t2 = (float)log(-(double)t1);
  return -t2;
}

// ---- per-step keys: jax.random.split(key(42), 2047), partitionable ----
__global__ void k_keys(uint32_t* __restrict__ keys) {
  int i = blockIdx.x * 256 + threadIdx.x;
  if (i >= NS) return;
  uint2 o = tf2x32(0u, 42u, 0u, (uint32_t)i);
  keys[2 * i] = o.x; keys[2 * i + 1] = o.y;
}

// ---- global max of weights = pher * heur^2 ----
__global__ void k_wmax(const float* __restrict__ pher, const float* __restrict__ heur,
                       uint32_t* __restrict__ wmax_bits) {
  int tid = blockIdx.x * blockDim.x + threadIdx.x;
  int stride = gridDim.x * blockDim.x;
  float m = 0.f;
  for (int i = tid; i < NN * NN; i += stride) {
    float h = heur[i];
    m = fmaxf(m, pher[i] * (h * h));
  }
  for (int off = 32; off; off >>= 1) m = fmaxf(m, __shfl_xor(m, off));
  if ((threadIdx.x & 63) == 0) atomicMax((unsigned int*)wmax_bits, __float_as_uint(m));
}

// ---- Phase 1: one wave per (step, ant) row; straight-line 32-slot threefry,
// all results in regs, ballot-based epilogue, no LDS. ----
__global__ __launch_bounds__(256, 6) void k_phase1(
    const uint32_t* __restrict__ keys, const uint32_t* __restrict__ wmax_bits,
    uint32_t* __restrict__ slots, OvfRec* __restrict__ ovf,
    uint32_t* __restrict__ ovf_cnt) {
  const int lane = threadIdx.x & 63;
  // wave-uniform row id, pinned to SGPR so key loads are scalar
  const int wFlat = __builtin_amdgcn_readfirstlane(
      (int)(blockIdx.x * 4 + (threadIdx.x >> 6)));
  const int s = wFlat >> 11;
  const int a = wFlat & 2047;
  const uint32_t k0 = keys[2 * s], k1 = keys[2 * s + 1];
  const uint32_t k2 = k0 ^ k1 ^ 0x1BD11BDAu;
  const uint32_t k2_1 = k2 + 1u, k0_2 = k0 + 2u, k1_3 = k1 + 3u;
  const uint32_t k2_4 = k2 + 4u, k0_5 = k0 + 5u;
  const float wmax = __uint_as_float(
      (uint32_t)__builtin_amdgcn_readfirstlane((int)*wmax_bits));

  // ctr for slot j = a*2048 + j*64 + lane ; x1_init = ctr + k1
  const uint32_t vbase_k1 = ((uint32_t)a << 11) + (uint32_t)lane + k1;

  uint32_t bits[32];
  uint32_t vmax = 0u;
#define TFR(r) { x0 += x1; x1 = __builtin_rotateleft32(x1, r) ^ x0; }
#pragma unroll
  for (int slot = 0; slot < 32; ++slot) {
    uint32_t x1 = vbase_k1 + (uint32_t)(slot << 6);
    uint32_t x0 = x1 + k0;                        // round 1 add (x0 was k0)
    x1 = __builtin_rotateleft32(x1, 13) ^ x0;     // round 1 tail
    TFR(15) TFR(26) TFR(6)
    x0 += k1; x1 += k2_1;
    TFR(17) TFR(29) TFR(16) TFR(24)
    x0 += k2; x1 += k0_2;
    TFR(13) TFR(15) TFR(26) TFR(6)
    x0 += k0; x1 += k1_3;
    TFR(17) TFR(29) TFR(16) TFR(24)
    x0 += k1; x1 += k2_4;
    TFR(13) TFR(15) TFR(26) TFR(6)
    x0 += k2; x1 += k0_5;
    uint32_t b = x0 ^ x1;
    bits[slot] = b;
    vmax = max(vmax, b);
  }
#undef TFR

  // wave max
  uint32_t M = vmax;
#pragma unroll
  for (int off = 32; off; off >>= 1)
    M = max(M, (uint32_t)__shfl_xor((int)M, off));

  // local-slope candidate window: du <= wEff * max(-u ln u) over [u*-du, u*]
  const uint32_t mstar = M >> 9;
  const float uStar = __uint_as_float(0x3f800000u | (mstar << 9)) - 1.0f;
  const float wEff = wmax + 1e-5f;
  uint32_t W;
  if (mstar < 64u) {
    W = 3200u;                       // never hit in practice; safe cap
  } else {
    float f0 = -uStar * logf(uStar);
    float d0 = wEff * f0 * 1.1f + 4e-6f;
    float uLo = uStar - d0;
    float bound;
    if (uLo <= 0.f) bound = 0.36788f;
    else {
      float fLo = -uLo * logf(uLo);
      bound = fmaxf(f0, fLo);
      if (uLo < 0.3679f && uStar > 0.3678f) bound = 0.36788f;  // spans 1/e
    }
    float du = wEff * bound * 1.02f + 2.4e-7f;
    W = (uint32_t)(du * 8388608.0f) + 2u;
  }
  const uint32_t thr = (mstar > W) ? ((mstar - W) << 9) : 0u;

  // candidate scan: 32 ballots, scalar bookkeeping
  int tc = 0; int winSlot = 0; unsigned long long winBal = 0ull;
#pragma unroll
  for (int slot = 0; slot < 32; ++slot) {
    unsigned long long bal = __ballot(bits[slot] >= thr);
    if (bal) { tc += (int)__popcll(bal); winSlot = slot; winBal = bal; }
  }

  const size_t si = (size_t)s * NA + a;
  const uint32_t winNode =
      ((uint32_t)winSlot << 6) | (uint32_t)__builtin_ctzll(winBal);
  if (tc == 1) {
    if (lane == 0) slots[si] = winNode;
  } else {  // rare (~2e-3): defer resolution to phase 2
    uint32_t idx = 0u;
    if (lane == 0) idx = atomicAdd(ovf_cnt, 1u);
    idx = (uint32_t)__shfl((int)idx, 0);
    if (idx < (uint32_t)OVF_CAP) {
      int off = 0;
#pragma unroll
      for (int slot = 0; slot < 32; ++slot) {
        bool c = bits[slot] >= thr;
        unsigned long long bal = __ballot(c);
        if (bal) {
          if (c) {
            int pos = off + (int)__popcll(bal & ((1ull << lane) - 1ull));
            if (pos < 16) {
              ovf[idx].n[pos] = ((uint32_t)slot << 6) | (uint32_t)lane;
              ovf[idx].g[pos] = gumbel_from_m(bits[slot] >> 9);
            }
          }
          off += (int)__popcll(bal);
        }
      }
      if (lane == 0) {
        ovf[idx].cnt = (uint32_t)min(tc, 16);
        slots[si] = 0x80000000u | idx;
      }
    } else if (lane == 0) {
      slots[si] = winNode;  // capacity fallback
    }
  }
}

// ---- Phase 2: 2048 independent ants replay the sequential walk ----
__global__ __launch_bounds__(256) void k_phase2(
    const uint32_t* __restrict__ slots, const OvfRec* __restrict__ ovf,
    const float* __restrict__ pher, const float* __restrict__ heur,
    const int* __restrict__ antpos, uint16_t* __restrict__ paths,
    float* __restrict__ plen_out) {
  __shared__ uint32_t vis[256][64];    // 64 KB: per-ant visited bitmap
  const int t = threadIdx.x;
  const int a = blockIdx.x * 256 + t;
  for (int i = 0; i < 64; ++i) vis[t][i] = 0u;
  int cur = antpos[a];
  vis[t][cur >> 5] |= 1u << (cur & 31);
  paths[(size_t)a * NN] = (uint16_t)cur;
  float plen = 0.f;
  for (int s = 0; s < NS; ++s) {
    uint32_t slot = slots[(size_t)s * NA + a];
    int nxt;
    if (!(slot & 0x80000000u)) {
      nxt = (int)slot;
    } else {
      const OvfRec& r = ovf[slot & 0x7fffffffu];
      float bs = -INFINITY; int bn = NN;
      int c = (int)r.cnt;
      for (int i = 0; i < c; ++i) {
        int n = (int)r.n[i];
        float wv = 0.f;
        if (((vis[t][n >> 5] >> (n & 31)) & 1u) == 0u) {
          float h = heur[(size_t)cur * NN + n];
          wv = pher[(size_t)cur * NN + n] * (h * h);
        }
        float sv = r.g[i] + wv;
        if (sv > bs || (sv == bs && n < bn)) { bs = sv; bn = n; }
      }
      nxt = bn;
    }
    plen += heur[(size_t)cur * NN + nxt];   // same fp32 order as reference
    vis[t][nxt >> 5] |= 1u << (nxt & 31);
    paths[(size_t)a * NN + s + 1] = (uint16_t)nxt;
    cur = nxt;
  }
  plen_out[a] = plen;
}

// ---- Final: argmin plen (first-index tie-break), broadcast best path x8 ----
__global__ void k_final(const float* __restrict__ plen,
                        const uint16_t* __restrict__ paths,
                        float* __restrict__ out) {
  __shared__ unsigned long long wred[4];
  const int t = threadIdx.x;  // 256
  unsigned long long best = ~0ull;
  for (int a = t; a < NA; a += 256) {
    unsigned long long k =
        ((unsigned long long)__float_as_uint(plen[a]) << 32) | (unsigned)a;
    if (k < best) best = k;
  }
  for (int off = 32; off; off >>= 1) {
    unsigned long long o = __shfl_xor(best, off);
    if (o < best) best = o;
  }
  if ((t & 63) == 0) wred[t >> 6] = best;
  __syncthreads();
  if (t == 0) {
    unsigned long long b = wred[0];
    for (int i = 1; i < 4; ++i) if (wred[i] < b) b = wred[i];
    wred[0] = b;
  }
  __syncthreads();
  const int bi = (int)(wred[0] & 0xffffffffu);
  const uint16_t* bp = paths + (size_t)bi * NN;
  for (int i = t; i < 8 * NN; i += 256) out[i] = (float)bp[i & (NN - 1)];
}

extern "C" void kernel_launch(void* const* d_in, const int* in_sizes, int n_in,
                              void* d_out, int out_size, void* d_ws, size_t ws_size,
                              hipStream_t stream) {
  (void)in_sizes; (void)n_in; (void)out_size; (void)ws_size;
  const float* pher   = (const float*)d_in[1];
  const float* heur   = (const float*)d_in[2];
  const int*   antpos = (const int*)d_in[3];
  char* ws = (char*)d_ws;
  uint32_t* wmax_bits = (uint32_t*)(ws + 0);
  uint32_t* ovf_cnt   = (uint32_t*)(ws + 4);
  uint32_t* keys      = (uint32_t*)(ws + OFF_KEYS);
  uint32_t* slots     = (uint32_t*)(ws + OFF_SLOTS);
  OvfRec*   ovf       = (OvfRec*)(ws + OFF_OVF);
  uint16_t* paths     = (uint16_t*)(ws + OFF_PATHS);
  float*    plen      = (float*)(ws + OFF_PLEN);

  hipMemsetAsync(d_ws, 0, 64, stream);  // wmax, ovf counter
  hipLaunchKernelGGL(k_keys, dim3(8), dim3(256), 0, stream, keys);
  hipLaunchKernelGGL(k_wmax, dim3(1024), dim3(256), 0, stream, pher, heur, wmax_bits);
  hipLaunchKernelGGL(k_phase1, dim3(NS * NA / 4), dim3(256), 0, stream,
                     keys, wmax_bits, slots, ovf, ovf_cnt);
  hipLaunchKernelGGL(k_phase2, dim3(NA / 256), dim3(256), 0, stream,
                     slots, ovf, pher, heur, antpos, paths, plen);
  hipLaunchKernelGGL(k_final, dim3(1), dim3(256), 0, stream,
                     plen, paths, (float*)d_out);
}